// Round 4
// baseline (16413.051 us; speedup 1.0000x reference)
//
#include <hip/hip_runtime.h>
#include <hip/hip_bf16.h>
#include <hip/hip_fp16.h>

typedef _Float16 h16;
typedef __attribute__((ext_vector_type(2))) _Float16 h16x2;
typedef __attribute__((ext_vector_type(4))) _Float16 h16x4;
typedef __attribute__((ext_vector_type(8))) _Float16 h16x8;
typedef __attribute__((ext_vector_type(4))) float f32x4;

#define MFMA16x32 __builtin_amdgcn_mfma_f32_16x16x32_f16

#if __has_builtin(__builtin_amdgcn_fdot2)
#define FDOT2(a,b,c) __builtin_amdgcn_fdot2((a),(b),(c),false)
#else
#define FDOT2(a,b,c) ((c) + (float)(a).x*(float)(b).x + (float)(a).y*(float)(b).y)
#endif

__device__ __forceinline__ float sigm(float x){ return 1.f/(1.f + __expf(-x)); }
__device__ __forceinline__ float tanh_fast(float x){ return 1.f - 2.f/(__expf(2.f*x) + 1.f); }
__device__ __forceinline__ h16x2 bch(float x){ return __builtin_bit_cast(h16x2, x); }

// ---------------- prep kernels ----------------

// pooled0[b*128+e] = sum_l seq[b][e][l]
__global__ void k_seq_sum(const float* __restrict__ seq, float* __restrict__ pooled0){
  int be = blockIdx.x;
  float s = 0.f;
  for (int l = threadIdx.x; l < 1024; l += 256) s += seq[(long)be*1024 + l];
  __shared__ float r[256];
  r[threadIdx.x] = s; __syncthreads();
  for (int k = 128; k; k >>= 1){ if (threadIdx.x < k) r[threadIdx.x] += r[threadIdx.x+k]; __syncthreads(); }
  if (threadIdx.x == 0) pooled0[be] = r[0];
}

// seq [16][128][1024] f32 -> seqT [16][1024][128] f16
__global__ void k_tr_seq(const float* __restrict__ seq, h16* __restrict__ seqT){
  __shared__ float t[128][65];
  int b = blockIdx.y, l0 = blockIdx.x*64;
  for (int i = threadIdx.x; i < 128*64; i += 256){
    int e = i >> 6, l = i & 63;
    t[e][l] = seq[((long)(b*128 + e))*1024 + l0 + l];
  }
  __syncthreads();
  for (int i = threadIdx.x; i < 64*64; i += 256){
    int l = i >> 6, ep = i & 63;
    h16x2 v; v.x = (h16)t[2*ep][l]; v.y = (h16)t[2*ep+1][l];
    *(h16x2*)&seqT[((long)(b*1024 + l0 + l))*128 + 2*ep] = v;
  }
}

// src [OC][CI][KW] f32 -> dst [OC][KW][CI] f16
__global__ void k_transw(const float* __restrict__ src, h16* __restrict__ dst, int OC, int CI, int KW){
  long total = (long)OC*CI*KW;
  for (long idx = (long)blockIdx.x*256 + threadIdx.x; idx < total; idx += (long)gridDim.x*256){
    long ci = idx % CI; long t = idx / CI; long kw = t % KW; long oc = t / KW;
    dst[idx] = (h16)src[(oc*CI + ci)*KW + kw];
  }
}

__global__ void k_prep_misc(const float* __restrict__ conv1_w, const float* __restrict__ wih,
                            const float* __restrict__ whh,
                            const float* __restrict__ bih, const float* __restrict__ bhh,
                            const float* __restrict__ aspp_bs, const float* __restrict__ bn_g,
                            const float* __restrict__ bn_b,
                            h16* __restrict__ W1b, h16* __restrict__ wihB, h16* __restrict__ whhB,
                            float* __restrict__ bsum, float* __restrict__ asb){
  int idx = blockIdx.x*256 + threadIdx.x;
  if (idx < 16*3840){ int cls = idx/3840; W1b[idx] = (h16)(cls < 9 ? conv1_w[idx] : 0.f); }
  if (idx < 2*1024*128) wihB[idx] = (h16)wih[idx];
  if (idx < 2*1024*256) whhB[idx] = (h16)whh[idx];
  if (idx < 2048) bsum[idx] = bih[idx] + bhh[idx];
  if (idx < 4*768){
    asb[idx]        = aspp_bs[idx];
    asb[3072 + idx] = rsqrtf(1.f + 1e-5f)*bn_g[idx];
    asb[6144 + idx] = bn_b[idx];
  }
}

// pooled[b][256] from hT [16][1024][256] f16
__global__ void k_poolT(const h16* __restrict__ hT, float* __restrict__ pooled){
  int b = blockIdx.x; int c = threadIdx.x & 255, lq = threadIdx.x >> 8;
  float s = 0.f;
  for (int l = lq*256; l < lq*256 + 256; ++l) s += (float)hT[((long)(b*1024 + l))*256 + c];
  __shared__ float r[1024];
  r[threadIdx.x] = s; __syncthreads();
  if (threadIdx.x < 256) pooled[b*256 + c] = r[c] + r[256+c] + r[512+c] + r[768+c];
}

// routing weights + per-sample biases for one gated layer
__global__ void k_route(const float* __restrict__ pooled, int Cin,
                        const float* __restrict__ rw, const float* __restrict__ rb,
                        const float* __restrict__ cond_b, const float* __restrict__ extra_b,
                        const float* __restrict__ gate_b, const float* __restrict__ c_add,
                        float* __restrict__ rbuf, float* __restrict__ biasA, float* __restrict__ biasB){
  __shared__ float rs[16][3]; __shared__ float rsum[16];
  int tid = threadIdx.x;
  if (tid < 48){
    int b = tid/3, e = tid%3;
    float s = 0.f;
    for (int c = 0; c < Cin; ++c) s += pooled[b*Cin + c]*rw[e*Cin + c];
    float v = sigm(s*(1.f/1034.f) + rb[e]);
    rs[b][e] = v; rbuf[b*3 + e] = v;
  }
  __syncthreads();
  if (tid < 16) rsum[tid] = rs[tid][0] + rs[tid][1] + rs[tid][2];
  __syncthreads();
  for (int i = tid; i < 16*256; i += 256){
    int b = i >> 8, o = i & 255;
    biasA[i] = rsum[b]*cond_b[o] + extra_b[o];
  }
  if (tid < 256) biasB[tid] = gate_b[tid] + c_add[tid];
}

// Wb[b][o][k][i] f16 = sum_e r[b][e] * W[e][o][i][k]
__global__ void k_mixw(const float* __restrict__ W, const float* __restrict__ rbuf,
                       h16* __restrict__ Wb, int Cin){
  int o = blockIdx.x, k = blockIdx.y;
  int i = threadIdx.x;
  if (i >= Cin) return;
  float w0 = W[(((long)(0*256 + o))*Cin + i)*11 + k];
  float w1 = W[(((long)(1*256 + o))*Cin + i)*11 + k];
  float w2 = W[(((long)(2*256 + o))*Cin + i)*11 + k];
  for (int b = 0; b < 16; ++b){
    float v = rbuf[b*3]*w0 + rbuf[b*3+1]*w1 + rbuf[b*3+2]*w2;
    Wb[(((long)(b*256 + o))*11 + k)*Cin + i] = (h16)v;
  }
}

// ---------------- gated conv layer (A-conv + gate-conv + gating + residual) ----------------
__launch_bounds__(256, 2)
__global__ void k_conv(const h16* __restrict__ xT, int Cin,
                       const h16* __restrict__ WbA, const h16* __restrict__ gwB,
                       const float* __restrict__ biasA, const float* __restrict__ biasB,
                       const h16* __restrict__ resT, h16* __restrict__ outT, int ostride){
  __shared__ h16 lds[138*136];
  int b = blockIdx.z, oc0 = blockIdx.y*64, l0 = blockIdx.x*128;
  int tid = threadIdx.x, lane = tid & 63, wave = tid >> 6;
  int wm = wave & 1, wn = wave >> 1, nl = lane & 15, quad = lane >> 4;
  f32x4 accA[2][4] = {}; f32x4 accB[2][4] = {};
  for (int cc0 = 0; cc0 < Cin; cc0 += 128){
    __syncthreads();
    for (int id = tid; id < 138*16; id += 256){
      int row = id >> 4, coff = (id & 15)*8;
      int time = l0 + row - 10;
      uint4 v = {0,0,0,0};
      if (time >= 0) v = *(const uint4*)&xT[((long)(b*1024 + time))*Cin + cc0 + coff];
      *(uint4*)&lds[row*136 + coff] = v;
    }
    __syncthreads();
    for (int kk = 0; kk < 11; ++kk){
      #pragma unroll
      for (int cc = 0; cc < 128; cc += 32){
        h16x8 bf[4];
        #pragma unroll
        for (int nt = 0; nt < 4; ++nt){
          int row = wn*64 + nt*16 + nl + kk;
          bf[nt] = *(const h16x8*)&lds[row*136 + cc + quad*8];
        }
        #pragma unroll
        for (int mt = 0; mt < 2; ++mt){
          int oc = oc0 + wm*32 + mt*16 + nl;
          h16x8 af = *(const h16x8*)&WbA[(((long)(b*256 + oc))*11 + kk)*Cin + cc0 + cc + quad*8];
          h16x8 gf = *(const h16x8*)&gwB[((long)oc*11 + kk)*Cin + cc0 + cc + quad*8];
          #pragma unroll
          for (int nt = 0; nt < 4; ++nt){
            accA[mt][nt] = MFMA16x32(af, bf[nt], accA[mt][nt], 0,0,0);
            accB[mt][nt] = MFMA16x32(gf, bf[nt], accB[mt][nt], 0,0,0);
          }
        }
      }
    }
  }
  #pragma unroll
  for (int mt = 0; mt < 2; ++mt){
    int ocb = oc0 + wm*32 + mt*16 + quad*4;
    float bA[4], bB[4];
    #pragma unroll
    for (int r = 0; r < 4; ++r){ bA[r] = biasA[b*256 + ocb + r]; bB[r] = biasB[ocb + r]; }
    #pragma unroll
    for (int nt = 0; nt < 4; ++nt){
      int t = l0 + wn*64 + nt*16 + nl;
      h16x4 pk;
      #pragma unroll
      for (int r = 0; r < 4; ++r){
        float a = accA[mt][nt][r] + bA[r];
        float g = accB[mt][nt][r] + bB[r];
        float h = a * sigm(g);
        if (resT) h += (float)resT[((long)(b*1024 + t))*256 + ocb + r];
        pk[r] = (h16)h;
      }
      *(h16x4*)&outT[((long)(b*1024 + t))*ostride + ocb] = pk;
    }
  }
}

// ---------------- LSTM input projection (writes f16 gates) ----------------
__launch_bounds__(256)
__global__ void k_xproj(const h16* __restrict__ seqT, const h16* __restrict__ wihB,
                        const float* __restrict__ bsum, h16* __restrict__ xg){
  int dir = blockIdx.z; int m0 = blockIdx.y*64; int n0 = blockIdx.x*128;
  int tid = threadIdx.x, lane = tid & 63, wave = tid >> 6;
  int wm = wave & 1, wn = wave >> 1, nl = lane & 15, quad = lane >> 4;
  f32x4 acc[2][4] = {};
  const h16* A = wihB + (long)dir*1024*128;
  for (int cc = 0; cc < 128; cc += 32){
    h16x8 bf[4];
    #pragma unroll
    for (int nt = 0; nt < 4; ++nt){
      int n = n0 + wn*64 + nt*16 + nl;
      bf[nt] = *(const h16x8*)&seqT[(long)n*128 + cc + quad*8];
    }
    #pragma unroll
    for (int mt = 0; mt < 2; ++mt){
      int m = m0 + wm*32 + mt*16 + nl;
      h16x8 af = *(const h16x8*)&A[(long)m*128 + cc + quad*8];
      #pragma unroll
      for (int nt = 0; nt < 4; ++nt)
        acc[mt][nt] = MFMA16x32(af, bf[nt], acc[mt][nt], 0,0,0);
    }
  }
  h16* xgd = xg + (long)dir*16*1024*1024;
  #pragma unroll
  for (int mt = 0; mt < 2; ++mt){
    int mb = m0 + wm*32 + mt*16 + quad*4;
    #pragma unroll
    for (int nt = 0; nt < 4; ++nt){
      int n = n0 + wn*64 + nt*16 + nl;
      h16x4 pk;
      #pragma unroll
      for (int r = 0; r < 4; ++r) pk[r] = (h16)(acc[mt][nt][r] + bsum[dir*1024 + mb + r]);
      *(h16x4*)&xgd[(long)n*1024 + mb] = pk;
    }
  }
}

// ---------------- LSTM sequential, self-contained: 32 blocks = (dir, b) ----------------
// 1024 threads = one gate row each; Whh streamed from L2 every step; h in LDS.
__launch_bounds__(1024, 1)
__global__ void k_lstm2(const h16* __restrict__ whhB, const h16* __restrict__ xg,
                        h16* __restrict__ hcatT){
  int p = blockIdx.x; int dir = p >> 4, b = p & 15;
  int row = threadIdx.x;             // gate row 0..1023 (i:0-255, f:256-511, g:512-767, o:768-1023)
  int g = row >> 8;
  __shared__ __align__(16) h16 hl[256];
  __shared__ float glds[1024];
  if (row < 256) hl[row] = (h16)0.f;
  float c = 0.f;                      // cell state, owned by threads row<256
  const f32x4* wv = (const f32x4*)(whhB + ((long)dir*1024 + row)*256); // 32 chunks of 8 f16
  const h16* xgd = xg + ((long)(dir*16 + b))*1024*1024;
  int step = dir ? -1 : 1;
  float nxt = (float)xgd[(long)(dir ? 1023 : 0)*1024 + row];
  __syncthreads();
  for (int t = 0; t < 1024; ++t){
    int phys = dir ? (1023 - t) : t;
    float acc = nxt;
    if (t < 1023) nxt = (float)xgd[(long)(phys + step)*1024 + row];
    const f32x4* hv = (const f32x4*)hl;
    float a0 = 0.f, a1 = 0.f;
    #pragma unroll 8
    for (int ch = 0; ch < 32; ch += 2){
      f32x4 w0 = wv[ch], w1 = wv[ch+1];
      f32x4 h0 = hv[ch], h1 = hv[ch+1];
      a0 = FDOT2(bch(w0.x), bch(h0.x), a0);
      a0 = FDOT2(bch(w0.y), bch(h0.y), a0);
      a0 = FDOT2(bch(w0.z), bch(h0.z), a0);
      a0 = FDOT2(bch(w0.w), bch(h0.w), a0);
      a1 = FDOT2(bch(w1.x), bch(h1.x), a1);
      a1 = FDOT2(bch(w1.y), bch(h1.y), a1);
      a1 = FDOT2(bch(w1.z), bch(h1.z), a1);
      a1 = FDOT2(bch(w1.w), bch(h1.w), a1);
    }
    acc += a0 + a1;
    glds[row] = (g == 2) ? tanh_fast(acc) : sigm(acc);
    __syncthreads();
    if (row < 256){
      float gi = glds[row], gf = glds[256 + row], gg = glds[512 + row], go = glds[768 + row];
      c = gf*c + gi*gg;
      float hh = go * tanh_fast(c);
      hcatT[((long)(b*1024 + phys))*768 + 256 + dir*256 + row] = (h16)hh;
      hl[row] = (h16)hh;
    }
    __syncthreads();
  }
}

// ---------------- head contribution from hcat (s=0): WRITES outacc ----------------
__launch_bounds__(256)
__global__ void k_head_hcat(const h16* __restrict__ hcatT, const h16* __restrict__ W1b,
                            float* __restrict__ outacc){
  int b = blockIdx.y, l0 = blockIdx.x*128;
  int tid = threadIdx.x, lane = tid & 63, wave = tid >> 6;
  int nl = lane & 15, quad = lane >> 4;
  f32x4 acc[2] = {};
  const h16* src = hcatT + (long)b*1024*768;
  for (int cc = 0; cc < 768; cc += 32){
    h16x8 af = *(const h16x8*)&W1b[(long)nl*3840 + cc + quad*8];
    #pragma unroll
    for (int nt = 0; nt < 2; ++nt){
      int l = l0 + wave*32 + nt*16 + nl;
      h16x8 bf = *(const h16x8*)&src[(long)l*768 + cc + quad*8];
      acc[nt] = MFMA16x32(af, bf, acc[nt], 0,0,0);
    }
  }
  #pragma unroll
  for (int nt = 0; nt < 2; ++nt){
    int l = l0 + wave*32 + nt*16 + nl;
    #pragma unroll
    for (int r = 0; r < 4; ++r){
      int cls = quad*4 + r;
      if (cls < 9) outacc[((long)(b*9 + cls))*1024 + l] = acc[nt][r];
    }
  }
}

// ---------------- ASPP (dil conv3 + relu + BN) fused with head partial ----------------
__launch_bounds__(256, 2)
__global__ void k_aspp_head(const h16* __restrict__ hcatT, const h16* __restrict__ awB,
                            const float* __restrict__ asb, const h16* __restrict__ W1b,
                            float* __restrict__ outacc){
  int jj = blockIdx.z >> 4, b = blockIdx.z & 15;
  int d = 1 << jj;
  int l0 = blockIdx.x*128, co0 = blockIdx.y*64;
  __shared__ h16 lds[144*136];
  int tid = threadIdx.x, lane = tid & 63, wave = tid >> 6;
  int wm = wave & 1, wn = wave >> 1, nl = lane & 15, quad = lane >> 4;
  f32x4 acc[2][4] = {};
  int nrows = 128 + 2*d;
  for (int cc0 = 0; cc0 < 768; cc0 += 128){
    __syncthreads();
    for (int id = tid; id < nrows*16; id += 256){
      int row = id >> 4, coff = (id & 15)*8;
      int time = l0 + row - d;
      uint4 v = {0,0,0,0};
      if (time >= 0 && time < 1024)
        v = *(const uint4*)&hcatT[((long)(b*1024 + time))*768 + cc0 + coff];
      *(uint4*)&lds[row*136 + coff] = v;
    }
    __syncthreads();
    for (int w = 0; w < 3; ++w){
      #pragma unroll
      for (int cc = 0; cc < 128; cc += 32){
        h16x8 bf[4];
        #pragma unroll
        for (int nt = 0; nt < 4; ++nt){
          int row = wn*64 + nt*16 + nl + w*d;
          bf[nt] = *(const h16x8*)&lds[row*136 + cc + quad*8];
        }
        #pragma unroll
        for (int mt = 0; mt < 2; ++mt){
          int co = co0 + wm*32 + mt*16 + nl;
          h16x8 af = *(const h16x8*)&awB[(((long)(jj*768 + co))*3 + w)*768 + cc0 + cc + quad*8];
          #pragma unroll
          for (int nt = 0; nt < 4; ++nt)
            acc[mt][nt] = MFMA16x32(af, bf[nt], acc[mt][nt], 0,0,0);
        }
      }
    }
  }
  // epilogue: bias + relu + BN, stash y tile into LDS in MFMA-B layout [l(128)][co(64)] pad->72
  const float* ab  = asb + jj*768;
  const float* as_ = asb + 3072 + jj*768;
  const float* at  = asb + 6144 + jj*768;
  __syncthreads();
  #pragma unroll
  for (int mt = 0; mt < 2; ++mt){
    int col = wm*32 + mt*16 + quad*4;        // local co
    int cob = co0 + col;                     // global co
    #pragma unroll
    for (int nt = 0; nt < 4; ++nt){
      int rowl = wn*64 + nt*16 + nl;         // local l
      h16x4 pk;
      #pragma unroll
      for (int r = 0; r < 4; ++r){
        float v = acc[mt][nt][r] + ab[cob + r];
        v = fmaxf(v, 0.f)*as_[cob + r] + at[cob + r];
        pk[r] = (h16)v;
      }
      *(h16x4*)&lds[rowl*72 + col] = pk;
    }
  }
  __syncthreads();
  // head partial: out[cls(16) x l(128)] += W1[cls, (jj+1)*768 + co0 .. +64] @ y
  f32x4 acc2[2] = {};
  #pragma unroll
  for (int kk = 0; kk < 2; ++kk){
    h16x8 af = *(const h16x8*)&W1b[(long)nl*3840 + (jj+1)*768 + co0 + kk*32 + quad*8];
    #pragma unroll
    for (int nt = 0; nt < 2; ++nt){
      int rowl = wave*32 + nt*16 + nl;
      h16x8 bf = *(const h16x8*)&lds[rowl*72 + kk*32 + quad*8];
      acc2[nt] = MFMA16x32(af, bf, acc2[nt], 0,0,0);
    }
  }
  #pragma unroll
  for (int nt = 0; nt < 2; ++nt){
    int l = l0 + wave*32 + nt*16 + nl;
    #pragma unroll
    for (int r = 0; r < 4; ++r){
      int cls = quad*4 + r;
      if (cls < 9) atomicAdd(&outacc[((long)(b*9 + cls))*1024 + l], acc2[nt][r]);
    }
  }
}

// ---------------- finalize: bias + log-sigmoid ----------------
__global__ void k_final(const float* __restrict__ outacc, const float* __restrict__ b1,
                        float* __restrict__ out){
  int i = blockIdx.x*256 + threadIdx.x;
  if (i >= 16*9*1024) return;
  int cls = (i >> 10) % 9;
  float x = outacc[i] + b1[cls];
  out[i] = fminf(x, 0.f) - log1pf(__expf(-fabsf(x)));
}

// ---------------- host ----------------
extern "C" void kernel_launch(void* const* d_in, const int* in_sizes, int n_in,
                              void* d_out, int out_size, void* d_ws, size_t ws_size,
                              hipStream_t stream){
  (void)in_sizes; (void)n_in; (void)out_size; (void)ws_size;
  const float* seq      = (const float*)d_in[0];
  const float* cond0_w  = (const float*)d_in[1];
  const float* cond0_b  = (const float*)d_in[2];
  const float* rout0_w  = (const float*)d_in[3];
  const float* rout0_b  = (const float*)d_in[4];
  const float* b0       = (const float*)d_in[5];
  const float* gate0_w  = (const float*)d_in[6];
  const float* gate0_b  = (const float*)d_in[7];
  const float* c0       = (const float*)d_in[8];
  const float* cond_ws  = (const float*)d_in[9];
  const float* cond_bs  = (const float*)d_in[10];
  const float* rout_ws  = (const float*)d_in[11];
  const float* rout_bs  = (const float*)d_in[12];
  const float* bs       = (const float*)d_in[13];
  const float* gate_ws  = (const float*)d_in[14];
  const float* gate_bs  = (const float*)d_in[15];
  const float* cs       = (const float*)d_in[16];
  const float* lstm_wih = (const float*)d_in[17];
  const float* lstm_whh = (const float*)d_in[18];
  const float* lstm_bih = (const float*)d_in[19];
  const float* lstm_bhh = (const float*)d_in[20];
  const float* aspp_ws  = (const float*)d_in[21];
  const float* aspp_bs  = (const float*)d_in[22];
  const float* bn_g     = (const float*)d_in[23];
  const float* bn_b     = (const float*)d_in[24];
  const float* conv1_w  = (const float*)d_in[25];
  const float* conv1_b  = (const float*)d_in[26];
  float* out = (float*)d_out;

  char* ws = (char*)d_ws;
  size_t off = 0;
  auto alloc = [&](size_t bytes)->char*{ char* p = ws + off; off += (bytes + 255) & ~(size_t)255; return p; };
  // long-lived (~45.5 MB)
  h16*   seqT    = (h16*)  alloc((size_t)16*1024*128*2);     // 4.19 MB
  float* pooled0 = (float*)alloc(16*128*4);
  float* pooled  = (float*)alloc(16*256*4);
  float* rbuf    = (float*)alloc(16*3*4);
  float* biasA   = (float*)alloc(16*256*4);
  float* biasB   = (float*)alloc(256*4);
  float* asb     = (float*)alloc(3*4*768*4);
  h16*   W1b     = (h16*)  alloc(16*3840*2);
  h16*   wihB    = (h16*)  alloc((size_t)2*1024*128*2);
  h16*   whhB    = (h16*)  alloc((size_t)2*1024*256*2);      // 1.05 MB
  float* bsum    = (float*)alloc(2*1024*4);
  float* outacc  = (float*)alloc((size_t)16*9*1024*4);       // 0.59 MB
  h16*   asppW   = (h16*)  alloc((size_t)4*768*3*768*2);     // 14.16 MB
  h16*   hcatT   = (h16*)  alloc((size_t)16*1024*768*2);     // 25.17 MB
  // arena (67.11 MB): conv-phase {Wb, gw, hbuf0..2} aliased by lstm-phase {xg}
  char*  arena   = alloc((size_t)67108864);
  h16*   Wb      = (h16*)(arena);                            // 23.07 MB
  h16*   gw      = (h16*)(arena + (size_t)23068672);         //  7.21 MB
  h16*   hbuf0   = (h16*)(arena + (size_t)30277632);         //  8.39 MB each
  h16*   hbuf1   = (h16*)(arena + (size_t)38666240);
  h16*   hbuf2   = (h16*)(arena + (size_t)47054848);
  h16*   xg      = (h16*)(arena);                            // 67.11 MB, after convs done

  k_seq_sum<<<2048,256,0,stream>>>(seq, pooled0);
  k_tr_seq<<<dim3(16,16),256,0,stream>>>(seq, seqT);
  const size_t GWS = (size_t)256*11*256;
  k_transw<<<512,256,0,stream>>>(gate0_w, gw, 256,128,11);
  for (int i = 1; i < 5; ++i)
    k_transw<<<512,256,0,stream>>>(gate_ws + (size_t)(i-1)*256*256*11, gw + i*GWS, 256,256,11);
  k_transw<<<2048,256,0,stream>>>(aspp_ws, asppW, 3072,768,3);
  k_prep_misc<<<2048,256,0,stream>>>(conv1_w, lstm_wih, lstm_whh, lstm_bih, lstm_bhh,
                                     aspp_bs, bn_g, bn_b, W1b, wihB, whhB, bsum, asb);

  // layer 0
  k_route<<<1,256,0,stream>>>(pooled0,128, rout0_w, rout0_b, cond0_b, b0, gate0_b, c0, rbuf, biasA, biasB);
  k_mixw<<<dim3(256,11),256,0,stream>>>(cond0_w, rbuf, Wb, 128);
  k_conv<<<dim3(8,4,16),256,0,stream>>>(seqT,128, Wb, gw, biasA, biasB, nullptr, hbuf0, 256);

  // layers 1..4
  const h16* ins[4]  = {hbuf0, hbuf1, hbuf2, hbuf0};
  const h16* res[4]  = {hbuf0, nullptr, hbuf1, nullptr};
  h16*       outs[4] = {hbuf1, hbuf2, hbuf0, hcatT};
  int        ostr[4] = {256, 256, 256, 768};
  for (int i = 0; i < 4; ++i){
    k_poolT<<<16,1024,0,stream>>>(ins[i], pooled);
    k_route<<<1,256,0,stream>>>(pooled,256, rout_ws + (size_t)i*3*256, rout_bs + i*3, cond_bs + (size_t)i*256,
                                bs + (size_t)i*256, gate_bs + (size_t)i*256, cs + (size_t)i*256, rbuf, biasA, biasB);
    k_mixw<<<dim3(256,11),256,0,stream>>>(cond_ws + (size_t)i*3*256*256*11, rbuf, Wb, 256);
    k_conv<<<dim3(8,4,16),256,0,stream>>>(ins[i],256, Wb, gw + (size_t)(i+1)*GWS, biasA, biasB, res[i], outs[i], ostr[i]);
  }

  // LSTM (xg overwrites conv arena — convs all done by here)
  k_xproj<<<dim3(128,16,2),256,0,stream>>>(seqT, wihB, bsum, xg);
  k_lstm2<<<32,1024,0,stream>>>(whhB, xg, hcatT);

  // head: s=0 (writes), ASPP fused head partials (atomicAdd), finalize
  k_head_hcat<<<dim3(8,16),256,0,stream>>>(hcatT, W1b, outacc);
  k_aspp_head<<<dim3(8,12,64),256,0,stream>>>(hcatT, asppW, asb, W1b, outacc);
  k_final<<<576,256,0,stream>>>(outacc, conv1_b, out);
}

// Round 5
// 3996.664 us; speedup vs baseline: 4.1067x; 4.1067x over previous
//
#include <hip/hip_runtime.h>
#include <hip/hip_bf16.h>
#include <hip/hip_fp16.h>

typedef _Float16 h16;
typedef __attribute__((ext_vector_type(2))) _Float16 h16x2;
typedef __attribute__((ext_vector_type(4))) _Float16 h16x4;
typedef __attribute__((ext_vector_type(8))) _Float16 h16x8;
typedef __attribute__((ext_vector_type(4))) float f32x4;

#define MFMA16x32 __builtin_amdgcn_mfma_f32_16x16x32_f16

#if __has_builtin(__builtin_amdgcn_fdot2)
#define FDOT2(a,b,c) __builtin_amdgcn_fdot2((a),(b),(c),false)
#else
#define FDOT2(a,b,c) ((c) + (float)(a).x*(float)(b).x + (float)(a).y*(float)(b).y)
#endif

__device__ __forceinline__ float sigm(float x){ return 1.f/(1.f + __expf(-x)); }
__device__ __forceinline__ float tanh_fast(float x){ return 1.f - 2.f/(__expf(2.f*x) + 1.f); }
__device__ __forceinline__ h16x2 bch(float x){ return __builtin_bit_cast(h16x2, x); }
__device__ __forceinline__ h16x2 bcu(unsigned x){ return __builtin_bit_cast(h16x2, x); }

// ---------------- prep kernels ----------------

// pooled0[b*128+e] = sum_l seq[b][e][l]
__global__ void k_seq_sum(const float* __restrict__ seq, float* __restrict__ pooled0){
  int be = blockIdx.x;
  float s = 0.f;
  for (int l = threadIdx.x; l < 1024; l += 256) s += seq[(long)be*1024 + l];
  __shared__ float r[256];
  r[threadIdx.x] = s; __syncthreads();
  for (int k = 128; k; k >>= 1){ if (threadIdx.x < k) r[threadIdx.x] += r[threadIdx.x+k]; __syncthreads(); }
  if (threadIdx.x == 0) pooled0[be] = r[0];
}

// seq [16][128][1024] f32 -> seqT [16][1024][128] f16
__global__ void k_tr_seq(const float* __restrict__ seq, h16* __restrict__ seqT){
  __shared__ float t[128][65];
  int b = blockIdx.y, l0 = blockIdx.x*64;
  for (int i = threadIdx.x; i < 128*64; i += 256){
    int e = i >> 6, l = i & 63;
    t[e][l] = seq[((long)(b*128 + e))*1024 + l0 + l];
  }
  __syncthreads();
  for (int i = threadIdx.x; i < 64*64; i += 256){
    int l = i >> 6, ep = i & 63;
    h16x2 v; v.x = (h16)t[2*ep][l]; v.y = (h16)t[2*ep+1][l];
    *(h16x2*)&seqT[((long)(b*1024 + l0 + l))*128 + 2*ep] = v;
  }
}

// src [OC][CI][KW] f32 -> dst [OC][KW][CI] f16
__global__ void k_transw(const float* __restrict__ src, h16* __restrict__ dst, int OC, int CI, int KW){
  long total = (long)OC*CI*KW;
  for (long idx = (long)blockIdx.x*256 + threadIdx.x; idx < total; idx += (long)gridDim.x*256){
    long ci = idx % CI; long t = idx / CI; long kw = t % KW; long oc = t / KW;
    dst[idx] = (h16)src[(oc*CI + ci)*KW + kw];
  }
}

__global__ void k_prep_misc(const float* __restrict__ conv1_w, const float* __restrict__ wih,
                            const float* __restrict__ whh,
                            const float* __restrict__ bih, const float* __restrict__ bhh,
                            const float* __restrict__ aspp_bs, const float* __restrict__ bn_g,
                            const float* __restrict__ bn_b,
                            h16* __restrict__ W1b, h16* __restrict__ wihB, h16* __restrict__ whhB,
                            float* __restrict__ bsum, float* __restrict__ asb){
  int idx = blockIdx.x*256 + threadIdx.x;
  if (idx < 16*3840){ int cls = idx/3840; W1b[idx] = (h16)(cls < 9 ? conv1_w[idx] : 0.f); }
  if (idx < 2*1024*128) wihB[idx] = (h16)wih[idx];
  if (idx < 2*1024*256) whhB[idx] = (h16)whh[idx];
  if (idx < 2048) bsum[idx] = bih[idx] + bhh[idx];
  if (idx < 4*768){
    asb[idx]        = aspp_bs[idx];
    asb[3072 + idx] = rsqrtf(1.f + 1e-5f)*bn_g[idx];
    asb[6144 + idx] = bn_b[idx];
  }
}

// pooled[b][256] from hT [16][1024][256] f16
__global__ void k_poolT(const h16* __restrict__ hT, float* __restrict__ pooled){
  int b = blockIdx.x; int c = threadIdx.x & 255, lq = threadIdx.x >> 8;
  float s = 0.f;
  for (int l = lq*256; l < lq*256 + 256; ++l) s += (float)hT[((long)(b*1024 + l))*256 + c];
  __shared__ float r[1024];
  r[threadIdx.x] = s; __syncthreads();
  if (threadIdx.x < 256) pooled[b*256 + c] = r[c] + r[256+c] + r[512+c] + r[768+c];
}

// routing weights + per-sample biases for one gated layer
__global__ void k_route(const float* __restrict__ pooled, int Cin,
                        const float* __restrict__ rw, const float* __restrict__ rb,
                        const float* __restrict__ cond_b, const float* __restrict__ extra_b,
                        const float* __restrict__ gate_b, const float* __restrict__ c_add,
                        float* __restrict__ rbuf, float* __restrict__ biasA, float* __restrict__ biasB){
  __shared__ float rs[16][3]; __shared__ float rsum[16];
  int tid = threadIdx.x;
  if (tid < 48){
    int b = tid/3, e = tid%3;
    float s = 0.f;
    for (int c = 0; c < Cin; ++c) s += pooled[b*Cin + c]*rw[e*Cin + c];
    float v = sigm(s*(1.f/1034.f) + rb[e]);
    rs[b][e] = v; rbuf[b*3 + e] = v;
  }
  __syncthreads();
  if (tid < 16) rsum[tid] = rs[tid][0] + rs[tid][1] + rs[tid][2];
  __syncthreads();
  for (int i = tid; i < 16*256; i += 256){
    int b = i >> 8, o = i & 255;
    biasA[i] = rsum[b]*cond_b[o] + extra_b[o];
  }
  if (tid < 256) biasB[tid] = gate_b[tid] + c_add[tid];
}

// Wb[b][o][k][i] f16 = sum_e r[b][e] * W[e][o][i][k]
__global__ void k_mixw(const float* __restrict__ W, const float* __restrict__ rbuf,
                       h16* __restrict__ Wb, int Cin){
  int o = blockIdx.x, k = blockIdx.y;
  int i = threadIdx.x;
  if (i >= Cin) return;
  float w0 = W[(((long)(0*256 + o))*Cin + i)*11 + k];
  float w1 = W[(((long)(1*256 + o))*Cin + i)*11 + k];
  float w2 = W[(((long)(2*256 + o))*Cin + i)*11 + k];
  for (int b = 0; b < 16; ++b){
    float v = rbuf[b*3]*w0 + rbuf[b*3+1]*w1 + rbuf[b*3+2]*w2;
    Wb[(((long)(b*256 + o))*11 + k)*Cin + i] = (h16)v;
  }
}

// ---------------- gated conv layer (A-conv + gate-conv + gating + residual) ----------------
__launch_bounds__(256, 2)
__global__ void k_conv(const h16* __restrict__ xT, int Cin,
                       const h16* __restrict__ WbA, const h16* __restrict__ gwB,
                       const float* __restrict__ biasA, const float* __restrict__ biasB,
                       const h16* __restrict__ resT, h16* __restrict__ outT, int ostride){
  __shared__ h16 lds[138*136];
  int b = blockIdx.z, oc0 = blockIdx.y*64, l0 = blockIdx.x*128;
  int tid = threadIdx.x, lane = tid & 63, wave = tid >> 6;
  int wm = wave & 1, wn = wave >> 1, nl = lane & 15, quad = lane >> 4;
  f32x4 accA[2][4] = {}; f32x4 accB[2][4] = {};
  for (int cc0 = 0; cc0 < Cin; cc0 += 128){
    __syncthreads();
    for (int id = tid; id < 138*16; id += 256){
      int row = id >> 4, coff = (id & 15)*8;
      int time = l0 + row - 10;
      uint4 v = {0,0,0,0};
      if (time >= 0) v = *(const uint4*)&xT[((long)(b*1024 + time))*Cin + cc0 + coff];
      *(uint4*)&lds[row*136 + coff] = v;
    }
    __syncthreads();
    for (int kk = 0; kk < 11; ++kk){
      #pragma unroll
      for (int cc = 0; cc < 128; cc += 32){
        h16x8 bf[4];
        #pragma unroll
        for (int nt = 0; nt < 4; ++nt){
          int row = wn*64 + nt*16 + nl + kk;
          bf[nt] = *(const h16x8*)&lds[row*136 + cc + quad*8];
        }
        #pragma unroll
        for (int mt = 0; mt < 2; ++mt){
          int oc = oc0 + wm*32 + mt*16 + nl;
          h16x8 af = *(const h16x8*)&WbA[(((long)(b*256 + oc))*11 + kk)*Cin + cc0 + cc + quad*8];
          h16x8 gf = *(const h16x8*)&gwB[((long)oc*11 + kk)*Cin + cc0 + cc + quad*8];
          #pragma unroll
          for (int nt = 0; nt < 4; ++nt){
            accA[mt][nt] = MFMA16x32(af, bf[nt], accA[mt][nt], 0,0,0);
            accB[mt][nt] = MFMA16x32(gf, bf[nt], accB[mt][nt], 0,0,0);
          }
        }
      }
    }
  }
  #pragma unroll
  for (int mt = 0; mt < 2; ++mt){
    int ocb = oc0 + wm*32 + mt*16 + quad*4;
    float bA[4], bB[4];
    #pragma unroll
    for (int r = 0; r < 4; ++r){ bA[r] = biasA[b*256 + ocb + r]; bB[r] = biasB[ocb + r]; }
    #pragma unroll
    for (int nt = 0; nt < 4; ++nt){
      int t = l0 + wn*64 + nt*16 + nl;
      h16x4 pk;
      #pragma unroll
      for (int r = 0; r < 4; ++r){
        float a = accA[mt][nt][r] + bA[r];
        float g = accB[mt][nt][r] + bB[r];
        float h = a * sigm(g);
        if (resT) h += (float)resT[((long)(b*1024 + t))*256 + ocb + r];
        pk[r] = (h16)h;
      }
      *(h16x4*)&outT[((long)(b*1024 + t))*ostride + ocb] = pk;
    }
  }
}

// ---------------- LSTM input projection (writes f16 gates) ----------------
__launch_bounds__(256)
__global__ void k_xproj(const h16* __restrict__ seqT, const h16* __restrict__ wihB,
                        const float* __restrict__ bsum, h16* __restrict__ xg){
  int dir = blockIdx.z; int m0 = blockIdx.y*64; int n0 = blockIdx.x*128;
  int tid = threadIdx.x, lane = tid & 63, wave = tid >> 6;
  int wm = wave & 1, wn = wave >> 1, nl = lane & 15, quad = lane >> 4;
  f32x4 acc[2][4] = {};
  const h16* A = wihB + (long)dir*1024*128;
  for (int cc = 0; cc < 128; cc += 32){
    h16x8 bf[4];
    #pragma unroll
    for (int nt = 0; nt < 4; ++nt){
      int n = n0 + wn*64 + nt*16 + nl;
      bf[nt] = *(const h16x8*)&seqT[(long)n*128 + cc + quad*8];
    }
    #pragma unroll
    for (int mt = 0; mt < 2; ++mt){
      int m = m0 + wm*32 + mt*16 + nl;
      h16x8 af = *(const h16x8*)&A[(long)m*128 + cc + quad*8];
      #pragma unroll
      for (int nt = 0; nt < 4; ++nt)
        acc[mt][nt] = MFMA16x32(af, bf[nt], acc[mt][nt], 0,0,0);
    }
  }
  h16* xgd = xg + (long)dir*16*1024*1024;
  #pragma unroll
  for (int mt = 0; mt < 2; ++mt){
    int mb = m0 + wm*32 + mt*16 + quad*4;
    #pragma unroll
    for (int nt = 0; nt < 4; ++nt){
      int n = n0 + wn*64 + nt*16 + nl;
      h16x4 pk;
      #pragma unroll
      for (int r = 0; r < 4; ++r) pk[r] = (h16)(acc[mt][nt][r] + bsum[dir*1024 + mb + r]);
      *(h16x4*)&xgd[(long)n*1024 + mb] = pk;
    }
  }
}

// ---------------- LSTM sequential: 32 blocks = (dir,b); 512 thr, 2 rows/thread ----------------
// Weights CU-resident: dwords [0,114) of each row in VGPRs (228 regs), tail [114,128) in LDS.
__launch_bounds__(512, 2)
__global__ void k_lstm3(const h16* __restrict__ whhB, const h16* __restrict__ xg,
                        h16* __restrict__ hcatT){
  int p = blockIdx.x; int dir = p >> 4, b = p & 15;
  int tid = threadIdx.x;
  int rA = tid, rB = tid + 512;       // rA: gate i/f row; rB: gate g/o row
  __shared__ __align__(16) h16 hl[256];
  __shared__ float glds[1024];
  __shared__ uint2 wlds[14*512];      // [c:0-6 rowA tail][c:7-13 rowB tail] x [tid]
  unsigned wA[114], wB[114];
  {
    const unsigned* a  = (const unsigned*)(whhB + ((long)dir*1024 + rA)*256);
    const unsigned* bb = (const unsigned*)(whhB + ((long)dir*1024 + rB)*256);
    #pragma unroll
    for (int c = 0; c < 114; ++c){ wA[c] = a[c]; wB[c] = bb[c]; }
    #pragma unroll
    for (int c = 0; c < 7; ++c){
      wlds[c*512 + tid]       = make_uint2(a[114 + 2*c],  a[115 + 2*c]);
      wlds[(7 + c)*512 + tid] = make_uint2(bb[114 + 2*c], bb[115 + 2*c]);
    }
  }
  if (tid < 256) hl[tid] = (h16)0.f;
  float cst = 0.f;
  const h16* xgd = xg + ((long)(dir*16 + b))*1024*1024;
  int step = dir ? -1 : 1;
  int first = dir ? 1023 : 0;
  float nxtA = (float)xgd[(long)first*1024 + rA];
  float nxtB = (float)xgd[(long)first*1024 + rB];
  __syncthreads();
  for (int t = 0; t < 1024; ++t){
    int phys = dir ? (1023 - t) : t;
    float aA = nxtA, aB = nxtB;
    if (t < 1023){
      nxtA = (float)xgd[(long)(phys + step)*1024 + rA];
      nxtB = (float)xgd[(long)(phys + step)*1024 + rB];
    }
    const f32x4* hv4 = (const f32x4*)hl;
    float sA0 = 0.f, sA1 = 0.f, sB0 = 0.f, sB1 = 0.f;
    #pragma unroll
    for (int ch = 0; ch < 28; ++ch){
      f32x4 h4 = hv4[ch];
      sA0 = FDOT2(bcu(wA[4*ch+0]), bch(h4.x), sA0);
      sA1 = FDOT2(bcu(wA[4*ch+1]), bch(h4.y), sA1);
      sA0 = FDOT2(bcu(wA[4*ch+2]), bch(h4.z), sA0);
      sA1 = FDOT2(bcu(wA[4*ch+3]), bch(h4.w), sA1);
      sB0 = FDOT2(bcu(wB[4*ch+0]), bch(h4.x), sB0);
      sB1 = FDOT2(bcu(wB[4*ch+1]), bch(h4.y), sB1);
      sB0 = FDOT2(bcu(wB[4*ch+2]), bch(h4.z), sB0);
      sB1 = FDOT2(bcu(wB[4*ch+3]), bch(h4.w), sB1);
    }
    {
      uint2 h2 = ((const uint2*)hl)[56];     // dwords 112,113
      sA0 = FDOT2(bcu(wA[112]), bcu(h2.x), sA0);
      sA1 = FDOT2(bcu(wA[113]), bcu(h2.y), sA1);
      sB0 = FDOT2(bcu(wB[112]), bcu(h2.x), sB0);
      sB1 = FDOT2(bcu(wB[113]), bcu(h2.y), sB1);
    }
    #pragma unroll
    for (int c2 = 0; c2 < 7; ++c2){          // dwords 114..127 from LDS
      uint2 h2 = ((const uint2*)hl)[57 + c2];
      uint2 wa = wlds[c2*512 + tid];
      uint2 wb = wlds[(7 + c2)*512 + tid];
      sA0 = FDOT2(bcu(wa.x), bcu(h2.x), sA0);
      sA1 = FDOT2(bcu(wa.y), bcu(h2.y), sA1);
      sB0 = FDOT2(bcu(wb.x), bcu(h2.x), sB0);
      sB1 = FDOT2(bcu(wb.y), bcu(h2.y), sB1);
    }
    aA += sA0 + sA1;
    aB += sB0 + sB1;
    glds[rA] = sigm(aA);                                   // i or f: sigmoid
    glds[rB] = (tid < 256) ? tanh_fast(aB) : sigm(aB);     // g: tanh, o: sigmoid
    __syncthreads();
    if (tid < 256){
      float gi = glds[tid], gf = glds[256 + tid], gg = glds[512 + tid], go = glds[768 + tid];
      cst = gf*cst + gi*gg;
      float hh = go * tanh_fast(cst);
      hcatT[((long)(b*1024 + phys))*768 + 256 + dir*256 + tid] = (h16)hh;
      hl[tid] = (h16)hh;
    }
    __syncthreads();
  }
}

// ---------------- head contribution from hcat (s=0): WRITES outacc ----------------
__launch_bounds__(256)
__global__ void k_head_hcat(const h16* __restrict__ hcatT, const h16* __restrict__ W1b,
                            float* __restrict__ outacc){
  int b = blockIdx.y, l0 = blockIdx.x*128;
  int tid = threadIdx.x, lane = tid & 63, wave = tid >> 6;
  int nl = lane & 15, quad = lane >> 4;
  f32x4 acc[2] = {};
  const h16* src = hcatT + (long)b*1024*768;
  for (int cc = 0; cc < 768; cc += 32){
    h16x8 af = *(const h16x8*)&W1b[(long)nl*3840 + cc + quad*8];
    #pragma unroll
    for (int nt = 0; nt < 2; ++nt){
      int l = l0 + wave*32 + nt*16 + nl;
      h16x8 bf = *(const h16x8*)&src[(long)l*768 + cc + quad*8];
      acc[nt] = MFMA16x32(af, bf, acc[nt], 0,0,0);
    }
  }
  #pragma unroll
  for (int nt = 0; nt < 2; ++nt){
    int l = l0 + wave*32 + nt*16 + nl;
    #pragma unroll
    for (int r = 0; r < 4; ++r){
      int cls = quad*4 + r;
      if (cls < 9) outacc[((long)(b*9 + cls))*1024 + l] = acc[nt][r];
    }
  }
}

// ---------------- ASPP (dil conv3 + relu + BN) fused with head partial ----------------
__launch_bounds__(256, 2)
__global__ void k_aspp_head(const h16* __restrict__ hcatT, const h16* __restrict__ awB,
                            const float* __restrict__ asb, const h16* __restrict__ W1b,
                            float* __restrict__ outacc){
  int jj = blockIdx.z >> 4, b = blockIdx.z & 15;
  int d = 1 << jj;
  int l0 = blockIdx.x*128, co0 = blockIdx.y*64;
  __shared__ h16 lds[144*136];
  int tid = threadIdx.x, lane = tid & 63, wave = tid >> 6;
  int wm = wave & 1, wn = wave >> 1, nl = lane & 15, quad = lane >> 4;
  f32x4 acc[2][4] = {};
  int nrows = 128 + 2*d;
  for (int cc0 = 0; cc0 < 768; cc0 += 128){
    __syncthreads();
    for (int id = tid; id < nrows*16; id += 256){
      int row = id >> 4, coff = (id & 15)*8;
      int time = l0 + row - d;
      uint4 v = {0,0,0,0};
      if (time >= 0 && time < 1024)
        v = *(const uint4*)&hcatT[((long)(b*1024 + time))*768 + cc0 + coff];
      *(uint4*)&lds[row*136 + coff] = v;
    }
    __syncthreads();
    for (int w = 0; w < 3; ++w){
      #pragma unroll
      for (int cc = 0; cc < 128; cc += 32){
        h16x8 bf[4];
        #pragma unroll
        for (int nt = 0; nt < 4; ++nt){
          int row = wn*64 + nt*16 + nl + w*d;
          bf[nt] = *(const h16x8*)&lds[row*136 + cc + quad*8];
        }
        #pragma unroll
        for (int mt = 0; mt < 2; ++mt){
          int co = co0 + wm*32 + mt*16 + nl;
          h16x8 af = *(const h16x8*)&awB[(((long)(jj*768 + co))*3 + w)*768 + cc0 + cc + quad*8];
          #pragma unroll
          for (int nt = 0; nt < 4; ++nt)
            acc[mt][nt] = MFMA16x32(af, bf[nt], acc[mt][nt], 0,0,0);
        }
      }
    }
  }
  // epilogue: bias + relu + BN, stash y tile into LDS in MFMA-B layout [l(128)][co(64)] pad->72
  const float* ab  = asb + jj*768;
  const float* as_ = asb + 3072 + jj*768;
  const float* at  = asb + 6144 + jj*768;
  __syncthreads();
  #pragma unroll
  for (int mt = 0; mt < 2; ++mt){
    int col = wm*32 + mt*16 + quad*4;        // local co
    int cob = co0 + col;                     // global co
    #pragma unroll
    for (int nt = 0; nt < 4; ++nt){
      int rowl = wn*64 + nt*16 + nl;         // local l
      h16x4 pk;
      #pragma unroll
      for (int r = 0; r < 4; ++r){
        float v = acc[mt][nt][r] + ab[cob + r];
        v = fmaxf(v, 0.f)*as_[cob + r] + at[cob + r];
        pk[r] = (h16)v;
      }
      *(h16x4*)&lds[rowl*72 + col] = pk;
    }
  }
  __syncthreads();
  // head partial: out[cls(16) x l(128)] += W1[cls, (jj+1)*768 + co0 .. +64] @ y
  f32x4 acc2[2] = {};
  #pragma unroll
  for (int kk = 0; kk < 2; ++kk){
    h16x8 af = *(const h16x8*)&W1b[(long)nl*3840 + (jj+1)*768 + co0 + kk*32 + quad*8];
    #pragma unroll
    for (int nt = 0; nt < 2; ++nt){
      int rowl = wave*32 + nt*16 + nl;
      h16x8 bf = *(const h16x8*)&lds[rowl*72 + kk*32 + quad*8];
      acc2[nt] = MFMA16x32(af, bf, acc2[nt], 0,0,0);
    }
  }
  #pragma unroll
  for (int nt = 0; nt < 2; ++nt){
    int l = l0 + wave*32 + nt*16 + nl;
    #pragma unroll
    for (int r = 0; r < 4; ++r){
      int cls = quad*4 + r;
      if (cls < 9) atomicAdd(&outacc[((long)(b*9 + cls))*1024 + l], acc2[nt][r]);
    }
  }
}

// ---------------- finalize: bias + log-sigmoid ----------------
__global__ void k_final(const float* __restrict__ outacc, const float* __restrict__ b1,
                        float* __restrict__ out){
  int i = blockIdx.x*256 + threadIdx.x;
  if (i >= 16*9*1024) return;
  int cls = (i >> 10) % 9;
  float x = outacc[i] + b1[cls];
  out[i] = fminf(x, 0.f) - log1pf(__expf(-fabsf(x)));
}

// ---------------- host ----------------
extern "C" void kernel_launch(void* const* d_in, const int* in_sizes, int n_in,
                              void* d_out, int out_size, void* d_ws, size_t ws_size,
                              hipStream_t stream){
  (void)in_sizes; (void)n_in; (void)out_size; (void)ws_size;
  const float* seq      = (const float*)d_in[0];
  const float* cond0_w  = (const float*)d_in[1];
  const float* cond0_b  = (const float*)d_in[2];
  const float* rout0_w  = (const float*)d_in[3];
  const float* rout0_b  = (const float*)d_in[4];
  const float* b0       = (const float*)d_in[5];
  const float* gate0_w  = (const float*)d_in[6];
  const float* gate0_b  = (const float*)d_in[7];
  const float* c0       = (const float*)d_in[8];
  const float* cond_ws  = (const float*)d_in[9];
  const float* cond_bs  = (const float*)d_in[10];
  const float* rout_ws  = (const float*)d_in[11];
  const float* rout_bs  = (const float*)d_in[12];
  const float* bs       = (const float*)d_in[13];
  const float* gate_ws  = (const float*)d_in[14];
  const float* gate_bs  = (const float*)d_in[15];
  const float* cs       = (const float*)d_in[16];
  const float* lstm_wih = (const float*)d_in[17];
  const float* lstm_whh = (const float*)d_in[18];
  const float* lstm_bih = (const float*)d_in[19];
  const float* lstm_bhh = (const float*)d_in[20];
  const float* aspp_ws  = (const float*)d_in[21];
  const float* aspp_bs  = (const float*)d_in[22];
  const float* bn_g     = (const float*)d_in[23];
  const float* bn_b     = (const float*)d_in[24];
  const float* conv1_w  = (const float*)d_in[25];
  const float* conv1_b  = (const float*)d_in[26];
  float* out = (float*)d_out;

  char* ws = (char*)d_ws;
  size_t off = 0;
  auto alloc = [&](size_t bytes)->char*{ char* p = ws + off; off += (bytes + 255) & ~(size_t)255; return p; };
  // long-lived (~45.5 MB)
  h16*   seqT    = (h16*)  alloc((size_t)16*1024*128*2);     // 4.19 MB
  float* pooled0 = (float*)alloc(16*128*4);
  float* pooled  = (float*)alloc(16*256*4);
  float* rbuf    = (float*)alloc(16*3*4);
  float* biasA   = (float*)alloc(16*256*4);
  float* biasB   = (float*)alloc(256*4);
  float* asb     = (float*)alloc(3*4*768*4);
  h16*   W1b     = (h16*)  alloc(16*3840*2);
  h16*   wihB    = (h16*)  alloc((size_t)2*1024*128*2);
  h16*   whhB    = (h16*)  alloc((size_t)2*1024*256*2);      // 1.05 MB
  float* bsum    = (float*)alloc(2*1024*4);
  float* outacc  = (float*)alloc((size_t)16*9*1024*4);       // 0.59 MB
  h16*   asppW   = (h16*)  alloc((size_t)4*768*3*768*2);     // 14.16 MB
  h16*   hcatT   = (h16*)  alloc((size_t)16*1024*768*2);     // 25.17 MB
  // arena (67.11 MB): conv-phase {Wb, gw, hbuf0..2} aliased by lstm-phase {xg}
  char*  arena   = alloc((size_t)67108864);
  h16*   Wb      = (h16*)(arena);                            // 23.07 MB
  h16*   gw      = (h16*)(arena + (size_t)23068672);         //  7.21 MB
  h16*   hbuf0   = (h16*)(arena + (size_t)30277632);         //  8.39 MB each
  h16*   hbuf1   = (h16*)(arena + (size_t)38666240);
  h16*   hbuf2   = (h16*)(arena + (size_t)47054848);
  h16*   xg      = (h16*)(arena);                            // 67.11 MB, after convs done

  k_seq_sum<<<2048,256,0,stream>>>(seq, pooled0);
  k_tr_seq<<<dim3(16,16),256,0,stream>>>(seq, seqT);
  const size_t GWS = (size_t)256*11*256;
  k_transw<<<512,256,0,stream>>>(gate0_w, gw, 256,128,11);
  for (int i = 1; i < 5; ++i)
    k_transw<<<512,256,0,stream>>>(gate_ws + (size_t)(i-1)*256*256*11, gw + i*GWS, 256,256,11);
  k_transw<<<2048,256,0,stream>>>(aspp_ws, asppW, 3072,768,3);
  k_prep_misc<<<2048,256,0,stream>>>(conv1_w, lstm_wih, lstm_whh, lstm_bih, lstm_bhh,
                                     aspp_bs, bn_g, bn_b, W1b, wihB, whhB, bsum, asb);

  // layer 0
  k_route<<<1,256,0,stream>>>(pooled0,128, rout0_w, rout0_b, cond0_b, b0, gate0_b, c0, rbuf, biasA, biasB);
  k_mixw<<<dim3(256,11),256,0,stream>>>(cond0_w, rbuf, Wb, 128);
  k_conv<<<dim3(8,4,16),256,0,stream>>>(seqT,128, Wb, gw, biasA, biasB, nullptr, hbuf0, 256);

  // layers 1..4
  const h16* ins[4]  = {hbuf0, hbuf1, hbuf2, hbuf0};
  const h16* res[4]  = {hbuf0, nullptr, hbuf1, nullptr};
  h16*       outs[4] = {hbuf1, hbuf2, hbuf0, hcatT};
  int        ostr[4] = {256, 256, 256, 768};
  for (int i = 0; i < 4; ++i){
    k_poolT<<<16,1024,0,stream>>>(ins[i], pooled);
    k_route<<<1,256,0,stream>>>(pooled,256, rout_ws + (size_t)i*3*256, rout_bs + i*3, cond_bs + (size_t)i*256,
                                bs + (size_t)i*256, gate_bs + (size_t)i*256, cs + (size_t)i*256, rbuf, biasA, biasB);
    k_mixw<<<dim3(256,11),256,0,stream>>>(cond_ws + (size_t)i*3*256*256*11, rbuf, Wb, 256);
    k_conv<<<dim3(8,4,16),256,0,stream>>>(ins[i],256, Wb, gw + (size_t)(i+1)*GWS, biasA, biasB, res[i], outs[i], ostr[i]);
  }

  // LSTM (xg overwrites conv arena — convs all done by here)
  k_xproj<<<dim3(128,16,2),256,0,stream>>>(seqT, wihB, bsum, xg);
  k_lstm3<<<32,512,0,stream>>>(whhB, xg, hcatT);

  // head: s=0 (writes), ASPP fused head partials (atomicAdd), finalize
  k_head_hcat<<<dim3(8,16),256,0,stream>>>(hcatT, W1b, outacc);
  k_aspp_head<<<dim3(8,12,64),256,0,stream>>>(hcatT, asppW, asb, W1b, outacc);
  k_final<<<576,256,0,stream>>>(outacc, conv1_b, out);
}